// Round 4
// baseline (133.416 us; speedup 1.0000x reference)
//
#include <hip/hip_runtime.h>
#include <hip/hip_bf16.h>
#include <cstddef>

#define GAT_B 16
#define GAT_N 2048
#define GAT_D 128
#define GAT_ROWS (GAT_B * GAT_N)
#define CH 64           // position-chunks per batch for partials
#define CL (GAT_N / CH) // 32 positions per chunk
#define RPB 32          // rows per sweep block
#define GAT_ALPHA 0.2f

// ---------------------------------------------------------------------------
// K1: h = x @ W (fp32), s1 = h . a1, s2 = h . a2
// 1024 blocks x 256 threads. Block tile: 32 rows x 128 cols; thread 4x4.
// W via ds_read_b128. LDS 80KB -> 2 blocks/CU.
// ---------------------------------------------------------------------------
__global__ __launch_bounds__(256, 2) void k1_gemm(const float* __restrict__ x,
                                                  const float* __restrict__ W,
                                                  const float* __restrict__ aa,
                                                  float* __restrict__ h,
                                                  float* __restrict__ s1,
                                                  float* __restrict__ s2) {
  __shared__ float Wl[128][128];  // [k][d] 64KB
  __shared__ float xs[32][128];   // 16KB
  const int tid = threadIdx.x;
  for (int i = tid * 4; i < 128 * 128; i += 1024)
    *(float4*)&Wl[i >> 7][i & 127] = *(const float4*)(W + i);
  const int row0 = blockIdx.x * 32;
  for (int i = tid * 4; i < 32 * 128; i += 1024)
    *(float4*)&xs[i >> 7][i & 127] = *(const float4*)(x + (size_t)row0 * GAT_D + i);
  __syncthreads();

  const int lane = tid & 63;
  const int c = (tid & 31) << 2;   // 4 cols
  const int rg = (tid >> 5) << 2;  // 4 rows

  float4 acc[4];
#pragma unroll
  for (int r = 0; r < 4; ++r) acc[r] = make_float4(0.f, 0.f, 0.f, 0.f);

#pragma unroll 2
  for (int k = 0; k < 128; k += 4) {
    float4 wv[4], xv[4];
#pragma unroll
    for (int kk = 0; kk < 4; ++kk) wv[kk] = *(const float4*)&Wl[k + kk][c];
#pragma unroll
    for (int r = 0; r < 4; ++r) xv[r] = *(const float4*)&xs[rg + r][k];
#pragma unroll
    for (int r = 0; r < 4; ++r) {
#pragma unroll
      for (int kk = 0; kk < 4; ++kk) {
        const float xr = ((const float*)&xv[r])[kk];
        acc[r].x = fmaf(xr, wv[kk].x, acc[r].x);
        acc[r].y = fmaf(xr, wv[kk].y, acc[r].y);
        acc[r].z = fmaf(xr, wv[kk].z, acc[r].z);
        acc[r].w = fmaf(xr, wv[kk].w, acc[r].w);
      }
    }
  }

  const float4 a1c = *(const float4*)(aa + c);
  const float4 a2c = *(const float4*)(aa + 128 + c);
#pragma unroll
  for (int r = 0; r < 4; ++r) {
    const int row = row0 + rg + r;
    *(float4*)(h + (size_t)row * GAT_D + c) = acc[r];
    float p1 = acc[r].x * a1c.x + acc[r].y * a1c.y + acc[r].z * a1c.z + acc[r].w * a1c.w;
    float p2 = acc[r].x * a2c.x + acc[r].y * a2c.y + acc[r].z * a2c.z + acc[r].w * a2c.w;
#pragma unroll
    for (int off = 1; off < 32; off <<= 1) {
      p1 += __shfl_xor(p1, off);
      p2 += __shfl_xor(p2, off);
    }
    if ((lane & 31) == 0) {
      s1[row] = p1;
      s2[row] = p2;
    }
  }
}

// ---------------------------------------------------------------------------
// K2: 32 blocks (2 per batch), 1024 threads.
//  even block: bitonic-sort s2 (w/ indices) -> s2s/idxs, + both den scans
//              (hierarchical shfl scan, 2 barriers).
//  odd block:  bitonic-sort key=-s1 (ascending == s1 descending, w/ row ids)
//              -> s1s (actual s1, desc) / rids.
// ---------------------------------------------------------------------------
__global__ __launch_bounds__(1024) void k2_sort(const float* __restrict__ s1,
                                                const float* __restrict__ s2,
                                                float* __restrict__ s2s,
                                                int* __restrict__ idxs,
                                                float* __restrict__ s1s,
                                                int* __restrict__ rids,
                                                float* __restrict__ preDenA,
                                                float* __restrict__ sufDenP) {
  __shared__ float v[2048];
  __shared__ int id[2048];
  __shared__ float wtotA[16];
  __shared__ float wtotP[16];
  const int tid = threadIdx.x;
  const int b = blockIdx.x >> 1;
  const int half = blockIdx.x & 1;
  const int i0 = tid, i1 = tid + 1024;
  if (half == 0) {
    v[i0] = s2[b * GAT_N + i0];
    v[i1] = s2[b * GAT_N + i1];
  } else {
    v[i0] = -s1[b * GAT_N + i0];
    v[i1] = -s1[b * GAT_N + i1];
  }
  id[i0] = i0;
  id[i1] = i1;
  for (int k = 2; k <= 2048; k <<= 1) {
    for (int j = k >> 1; j > 0; j >>= 1) {
      __syncthreads();
      const int i = ((tid & ~(j - 1)) << 1) | (tid & (j - 1));
      const int ixj = i | j;
      const bool up = (i & k) == 0;
      const float va = v[i], vb = v[ixj];
      if (up ? (va > vb) : (va < vb)) {
        v[i] = vb;
        v[ixj] = va;
        const int ta = id[i];
        id[i] = id[ixj];
        id[ixj] = ta;
      }
    }
  }
  __syncthreads();
  if (half == 1) {
    s1s[b * GAT_N + i0] = -v[i0];
    s1s[b * GAT_N + i1] = -v[i1];
    rids[b * GAT_N + i0] = id[i0];
    rids[b * GAT_N + i1] = id[i1];
    return;
  }
  s2s[b * GAT_N + i0] = v[i0];
  s2s[b * GAT_N + i1] = v[i1];
  idxs[b * GAT_N + i0] = id[i0];
  idxs[b * GAT_N + i1] = id[i1];

  // hierarchical scan: thread owns ascending pair (2t,2t+1) for preDenA and
  // descending pair (2047-2t, 2046-2t) for sufDenP.
  const int lane = tid & 63, w = tid >> 6;
  const float aL = __expf(GAT_ALPHA * v[2 * tid]);
  const float aR = __expf(GAT_ALPHA * v[2 * tid + 1]);
  const float pL = __expf(v[2047 - 2 * tid]);
  const float pR = __expf(v[2046 - 2 * tid]);
  float sA = aL + aR, sP = pL + pR;
#pragma unroll
  for (int off = 1; off < 64; off <<= 1) {
    const float tA = __shfl_up(sA, off);
    const float tP = __shfl_up(sP, off);
    if (lane >= off) {
      sA += tA;
      sP += tP;
    }
  }
  if (lane == 63) {
    wtotA[w] = sA;
    wtotP[w] = sP;
  }
  __syncthreads();
  float offA = 0.f, offP = 0.f;
  for (int ww = 0; ww < w; ++ww) {
    offA += wtotA[ww];
    offP += wtotP[ww];
  }
  const float inclA = offA + sA;
  const float inclP = offP + sP;
  preDenA[b * GAT_N + 2 * tid] = inclA - aR;
  preDenA[b * GAT_N + 2 * tid + 1] = inclA;
  sufDenP[b * GAT_N + 2047 - 2 * tid] = inclP - pR;
  sufDenP[b * GAT_N + 2046 - 2 * tid] = inclP;
}

// ---------------------------------------------------------------------------
// K3: per-(batch,chunk) partial sums of w*h over the chunk (both weightings).
// ---------------------------------------------------------------------------
__global__ __launch_bounds__(128) void k3_partial(const float* __restrict__ h,
                                                  const float* __restrict__ s2s,
                                                  const int* __restrict__ idxs,
                                                  float* __restrict__ partP,
                                                  float* __restrict__ partA) {
  const int b = blockIdx.x >> 6, c = blockIdx.x & (CH - 1);
  const int d = threadIdx.x;
  const int q0 = c * CL;
  const float* s2sb = s2s + b * GAT_N;
  const int* idxb = idxs + b * GAT_N;
  const float* hb = h + (size_t)b * GAT_N * GAT_D;
  float accP = 0.f, accA = 0.f;
#pragma unroll 4
  for (int q = q0; q < q0 + CL; ++q) {
    const float sv = s2sb[q];
    const int j = idxb[q];
    const float hv = hb[(size_t)j * GAT_D + d];
    accP = fmaf(__expf(sv), hv, accP);
    accA = fmaf(__expf(GAT_ALPHA * sv), hv, accA);
  }
  partP[(b * CH + c) * GAT_D + d] = accP;
  partA[(b * CH + c) * GAT_D + d] = accA;
}

// ---------------------------------------------------------------------------
// K4 (fused former K4+K5): merge-walk sweep.
// Block = 128 threads (one d each) x 32 sorted rows (s1 descending -> p
// ascending). Prefix walk (alpha branch) ascends q capturing accA at
// q == p_i - 1; suffix walk (plain branch) descends capturing accP at
// q == p_i. Chunk partials (K3) give the walk bases. All contrib arrays
// statically indexed (full unroll). No PreA/SufP materialization.
// ---------------------------------------------------------------------------
__global__ __launch_bounds__(128) void k4_sweep(const float* __restrict__ h,
                                                const float* __restrict__ s2s,
                                                const int* __restrict__ idxs,
                                                const float* __restrict__ s1s,
                                                const int* __restrict__ rids,
                                                const float* __restrict__ partP,
                                                const float* __restrict__ partA,
                                                const float* __restrict__ preDenA,
                                                const float* __restrict__ sufDenP,
                                                float* __restrict__ out) {
  const int b = blockIdx.x >> 6, c = blockIdx.x & 63;
  const int d = threadIdx.x;
  __shared__ int pS[RPB];
  __shared__ int ridS[RPB];
  __shared__ float e1S[RPB], e2S[RPB], invS[RPB];
  const float* s2sb = s2s + b * GAT_N;
  if (d < RPB) {
    const int j = c * RPB + d;
    const float s1v = s1s[b * GAT_N + j];
    ridS[d] = rids[b * GAT_N + j];
    const float t = -s1v;
    int lo = 0, hi = GAT_N;
    while (lo < hi) {
      const int mid = (lo + hi) >> 1;
      if (s2sb[mid] < t)
        lo = mid + 1;
      else
        hi = mid;
    }
    pS[d] = lo;
    const float e1 = __expf(s1v), e2 = __expf(GAT_ALPHA * s1v);
    e1S[d] = e1;
    e2S[d] = e2;
    float den = 0.f;
    if (lo < GAT_N) den += e1 * sufDenP[b * GAT_N + lo];
    if (lo > 0) den += e2 * preDenA[b * GAT_N + lo - 1];
    invS[d] = 1.f / den;
  }
  __syncthreads();

  const int* idxb = idxs + b * GAT_N;
  const float* hb = h + (size_t)b * GAT_N * GAT_D;

  const int p0 = pS[0];  // min p (rows sorted so p ascending)
  int pmaxValid = -1;    // largest p < N
  for (int i = 0; i < RPB; ++i) {
    const int pi = pS[i];
    if (pi < GAT_N && pi > pmaxValid) pmaxValid = pi;
  }

  // ---- prefix walk (alpha branch): accA(q) = sum_{q'<=q} exp(a*s2s)*h ----
  const int cstart = p0 / CL;
  float accA = 0.f;
  for (int cc = 0; cc < cstart; ++cc) accA += partA[(b * CH + cc) * GAT_D + d];
  int q = cstart * CL - 1;
  float contribA[RPB];
#pragma unroll
  for (int i = 0; i < RPB; ++i) {
    const int target = pS[i] - 1;
    while (q < target) {
      ++q;
      accA = fmaf(__expf(GAT_ALPHA * s2sb[q]), hb[(size_t)idxb[q] * GAT_D + d], accA);
    }
    contribA[i] = (pS[i] > 0) ? e2S[i] * accA : 0.f;
  }

  // ---- suffix walk (plain branch): accP(q) = sum_{q'>=q} exp(s2s)*h ----
  const int cend = (pmaxValid >= 0) ? (pmaxValid / CL + 1) : CH;
  float accP = 0.f;
  for (int cc = cend; cc < CH; ++cc) accP += partP[(b * CH + cc) * GAT_D + d];
  q = cend * CL;
  float contribP[RPB];
#pragma unroll
  for (int i = RPB - 1; i >= 0; --i) {
    const int target = pS[i];
    while (q > target) {
      --q;
      accP = fmaf(__expf(s2sb[q]), hb[(size_t)idxb[q] * GAT_D + d], accP);
    }
    contribP[i] = (pS[i] < GAT_N) ? e1S[i] * accP : 0.f;
  }

#pragma unroll
  for (int i = 0; i < RPB; ++i) {
    out[((size_t)b * GAT_N + ridS[i]) * GAT_D + d] =
        fmaxf((contribA[i] + contribP[i]) * invS[i], 0.f);
  }
}

extern "C" void kernel_launch(void* const* d_in, const int* in_sizes, int n_in,
                              void* d_out, int out_size, void* d_ws, size_t ws_size,
                              hipStream_t stream) {
  (void)in_sizes;
  (void)n_in;
  (void)out_size;
  const float* x = (const float*)d_in[0];
  const float* W = (const float*)d_in[1];
  const float* a = (const float*)d_in[2];
  float* out = (float*)d_out;
  float* wsf = (float*)d_ws;

  const size_t HN = (size_t)GAT_ROWS * GAT_D;
  size_t o = 0;
  float* s1v = wsf + o;     o += GAT_ROWS;
  float* s2v = wsf + o;     o += GAT_ROWS;
  float* s2s = wsf + o;     o += GAT_ROWS;
  int* idxs = (int*)(wsf + o); o += GAT_ROWS;
  float* s1s = wsf + o;     o += GAT_ROWS;
  int* rids = (int*)(wsf + o); o += GAT_ROWS;
  float* preDenA = wsf + o; o += GAT_ROWS;
  float* sufDenP = wsf + o; o += GAT_ROWS;
  float* partP = wsf + o;   o += GAT_B * CH * GAT_D;
  float* partA = wsf + o;   o += GAT_B * CH * GAT_D;
  float* h;
  if (ws_size >= (o + HN) * sizeof(float)) {
    h = wsf + o;
  } else {
    h = out;  // sweep writes out only at the very end; but prefer ws
  }

  k1_gemm<<<1024, 256, 0, stream>>>(x, W, a, h, s1v, s2v);
  k2_sort<<<2 * GAT_B, 1024, 0, stream>>>(s1v, s2v, s2s, idxs, s1s, rids, preDenA, sufDenP);
  k3_partial<<<GAT_B * CH, 128, 0, stream>>>(h, s2s, idxs, partP, partA);
  k4_sweep<<<GAT_B * 64, 128, 0, stream>>>(h, s2s, idxs, s1s, rids, partP, partA,
                                           preDenA, sufDenP, out);
}

// Round 5
// 91.187 us; speedup vs baseline: 1.4631x; 1.4631x over previous
//
#include <hip/hip_runtime.h>
#include <hip/hip_bf16.h>
#include <cstddef>

#define GAT_B 16
#define GAT_N 2048
#define GAT_D 128
#define GAT_ROWS (GAT_B * GAT_N)
#define CH 128          // position-chunks per batch
#define CL 16           // positions per chunk
#define GAT_ALPHA 0.2f

// ---------------------------------------------------------------------------
// K1: h = x @ W (fp32), s1 = h . a1, s2 = h . a2
// 1024 blocks x 256 threads. Block tile: 32 rows x 128 cols; thread 4x4.
// W via ds_read_b128. LDS 80KB -> 2 blocks/CU.
// ---------------------------------------------------------------------------
__global__ __launch_bounds__(256, 2) void k1_gemm(const float* __restrict__ x,
                                                  const float* __restrict__ W,
                                                  const float* __restrict__ aa,
                                                  float* __restrict__ h,
                                                  float* __restrict__ s1,
                                                  float* __restrict__ s2) {
  __shared__ float Wl[128][128];  // [k][d] 64KB
  __shared__ float xs[32][128];   // 16KB
  const int tid = threadIdx.x;
  for (int i = tid * 4; i < 128 * 128; i += 1024)
    *(float4*)&Wl[i >> 7][i & 127] = *(const float4*)(W + i);
  const int row0 = blockIdx.x * 32;
  for (int i = tid * 4; i < 32 * 128; i += 1024)
    *(float4*)&xs[i >> 7][i & 127] = *(const float4*)(x + (size_t)row0 * GAT_D + i);
  __syncthreads();

  const int lane = tid & 63;
  const int c = (tid & 31) << 2;   // 4 cols
  const int rg = (tid >> 5) << 2;  // 4 rows

  float4 acc[4];
#pragma unroll
  for (int r = 0; r < 4; ++r) acc[r] = make_float4(0.f, 0.f, 0.f, 0.f);

#pragma unroll 2
  for (int k = 0; k < 128; k += 4) {
    float4 wv[4], xv[4];
#pragma unroll
    for (int kk = 0; kk < 4; ++kk) wv[kk] = *(const float4*)&Wl[k + kk][c];
#pragma unroll
    for (int r = 0; r < 4; ++r) xv[r] = *(const float4*)&xs[rg + r][k];
#pragma unroll
    for (int r = 0; r < 4; ++r) {
#pragma unroll
      for (int kk = 0; kk < 4; ++kk) {
        const float xr = ((const float*)&xv[r])[kk];
        acc[r].x = fmaf(xr, wv[kk].x, acc[r].x);
        acc[r].y = fmaf(xr, wv[kk].y, acc[r].y);
        acc[r].z = fmaf(xr, wv[kk].z, acc[r].z);
        acc[r].w = fmaf(xr, wv[kk].w, acc[r].w);
      }
    }
  }

  const float4 a1c = *(const float4*)(aa + c);
  const float4 a2c = *(const float4*)(aa + 128 + c);
#pragma unroll
  for (int r = 0; r < 4; ++r) {
    const int row = row0 + rg + r;
    *(float4*)(h + (size_t)row * GAT_D + c) = acc[r];
    float p1 = acc[r].x * a1c.x + acc[r].y * a1c.y + acc[r].z * a1c.z + acc[r].w * a1c.w;
    float p2 = acc[r].x * a2c.x + acc[r].y * a2c.y + acc[r].z * a2c.z + acc[r].w * a2c.w;
#pragma unroll
    for (int off = 1; off < 32; off <<= 1) {
      p1 += __shfl_xor(p1, off);
      p2 += __shfl_xor(p2, off);
    }
    if ((lane & 31) == 0) {
      s1[row] = p1;
      s2[row] = p2;
    }
  }
}

// ---------------------------------------------------------------------------
// K2: 32 blocks (2 per batch), 1024 threads.
//  even block: bitonic-sort s2 (w/ indices) -> s2s/idxs, exp weights wA/wP,
//              + both den scans (hierarchical shfl scan, 2 barriers).
//  odd block:  bitonic-sort key=-s1 (ascending == s1 descending, w/ row ids)
//              -> s1s (actual s1, desc) / rids.
// ---------------------------------------------------------------------------
__global__ __launch_bounds__(1024) void k2_sort(const float* __restrict__ s1,
                                                const float* __restrict__ s2,
                                                float* __restrict__ s2s,
                                                int* __restrict__ idxs,
                                                float* __restrict__ s1s,
                                                int* __restrict__ rids,
                                                float* __restrict__ wA,
                                                float* __restrict__ wP,
                                                float* __restrict__ preDenA,
                                                float* __restrict__ sufDenP) {
  __shared__ float v[2048];
  __shared__ int id[2048];
  __shared__ float wtotA[16];
  __shared__ float wtotP[16];
  const int tid = threadIdx.x;
  const int b = blockIdx.x >> 1;
  const int half = blockIdx.x & 1;
  const int i0 = tid, i1 = tid + 1024;
  if (half == 0) {
    v[i0] = s2[b * GAT_N + i0];
    v[i1] = s2[b * GAT_N + i1];
  } else {
    v[i0] = -s1[b * GAT_N + i0];
    v[i1] = -s1[b * GAT_N + i1];
  }
  id[i0] = i0;
  id[i1] = i1;
  for (int k = 2; k <= 2048; k <<= 1) {
    for (int j = k >> 1; j > 0; j >>= 1) {
      __syncthreads();
      const int i = ((tid & ~(j - 1)) << 1) | (tid & (j - 1));
      const int ixj = i | j;
      const bool up = (i & k) == 0;
      const float va = v[i], vb = v[ixj];
      if (up ? (va > vb) : (va < vb)) {
        v[i] = vb;
        v[ixj] = va;
        const int ta = id[i];
        id[i] = id[ixj];
        id[ixj] = ta;
      }
    }
  }
  __syncthreads();
  if (half == 1) {
    s1s[b * GAT_N + i0] = -v[i0];
    s1s[b * GAT_N + i1] = -v[i1];
    rids[b * GAT_N + i0] = id[i0];
    rids[b * GAT_N + i1] = id[i1];
    return;
  }
  s2s[b * GAT_N + i0] = v[i0];
  s2s[b * GAT_N + i1] = v[i1];
  idxs[b * GAT_N + i0] = id[i0];
  idxs[b * GAT_N + i1] = id[i1];

  // hierarchical scan: thread owns ascending pair (2t,2t+1) for preDenA and
  // descending pair (2047-2t, 2046-2t) for sufDenP. Weights stored for K3/K5.
  const int lane = tid & 63, w = tid >> 6;
  const float aL = __expf(GAT_ALPHA * v[2 * tid]);
  const float aR = __expf(GAT_ALPHA * v[2 * tid + 1]);
  const float pL = __expf(v[2047 - 2 * tid]);
  const float pR = __expf(v[2046 - 2 * tid]);
  wA[b * GAT_N + 2 * tid] = aL;
  wA[b * GAT_N + 2 * tid + 1] = aR;
  wP[b * GAT_N + 2047 - 2 * tid] = pL;
  wP[b * GAT_N + 2046 - 2 * tid] = pR;
  float sA = aL + aR, sP = pL + pR;
#pragma unroll
  for (int off = 1; off < 64; off <<= 1) {
    const float tA = __shfl_up(sA, off);
    const float tP = __shfl_up(sP, off);
    if (lane >= off) {
      sA += tA;
      sP += tP;
    }
  }
  if (lane == 63) {
    wtotA[w] = sA;
    wtotP[w] = sP;
  }
  __syncthreads();
  float offA = 0.f, offP = 0.f;
  for (int ww = 0; ww < w; ++ww) {
    offA += wtotA[ww];
    offP += wtotP[ww];
  }
  const float inclA = offA + sA;
  const float inclP = offP + sP;
  preDenA[b * GAT_N + 2 * tid] = inclA - aR;
  preDenA[b * GAT_N + 2 * tid + 1] = inclA;
  sufDenP[b * GAT_N + 2047 - 2 * tid] = inclP - pR;
  sufDenP[b * GAT_N + 2046 - 2 * tid] = inclP;
}

// ---------------------------------------------------------------------------
// K3: permute h into sorted order (hs[q] = h[idx[q]]) and per-chunk partial
// sums of w*hs. One block per (batch, chunk of 16 positions), 128 threads.
// Gather-read of h happens exactly once here; everything downstream streams.
// ---------------------------------------------------------------------------
__global__ __launch_bounds__(128) void k3_permute(const float* __restrict__ h,
                                                  const int* __restrict__ idxs,
                                                  const float* __restrict__ wA,
                                                  const float* __restrict__ wP,
                                                  float* __restrict__ hs,
                                                  float* __restrict__ partA,
                                                  float* __restrict__ partP) {
  const int b = blockIdx.x >> 7, c = blockIdx.x & (CH - 1);
  const int d = threadIdx.x;
  const int q0 = c * CL;
  const int* idxb = idxs + b * GAT_N;
  const float* hb = h + (size_t)b * GAT_N * GAT_D;
  float accA = 0.f, accP = 0.f;
#pragma unroll
  for (int qq = 0; qq < CL; ++qq) {
    const int q = q0 + qq;
    const int j = idxb[q];
    const float hv = hb[(size_t)j * GAT_D + d];
    hs[((size_t)b * GAT_N + q) * GAT_D + d] = hv;
    accA = fmaf(wA[b * GAT_N + q], hv, accA);
    accP = fmaf(wP[b * GAT_N + q], hv, accP);
  }
  partA[(b * CH + c) * GAT_D + d] = accA;
  partP[(b * CH + c) * GAT_D + d] = accP;
}

// ---------------------------------------------------------------------------
// K3b: 32 blocks (2 per batch), 1024 threads.
//  role 0: scan chunk partials into bases.
//    baseA[c][d] = sum_{q < c*CL} wA*hs   (exclusive prefix; c in [0,CH])
//    baseP[c][d] = sum_{q >= (c+1)*CL}    (exclusive suffix; c in [0,CH))
//    thread (g,d): 8 groups x 16 chunks, group totals via LDS.
//  role 1: per-row prep: binary search p (s2s in LDS), den, c1=e1/den,
//    c2=e2/den. Removes per-wave redundant searches from K5.
// ---------------------------------------------------------------------------
__global__ __launch_bounds__(1024) void k3b_prep(const float* __restrict__ s1s,
                                                 const float* __restrict__ s2s,
                                                 const float* __restrict__ preDenA,
                                                 const float* __restrict__ sufDenP,
                                                 const float* __restrict__ partA,
                                                 const float* __restrict__ partP,
                                                 float* __restrict__ baseA,
                                                 float* __restrict__ baseP,
                                                 int* __restrict__ pArr,
                                                 float* __restrict__ c1,
                                                 float* __restrict__ c2) {
  __shared__ float totA[8][128];
  __shared__ float totP[8][128];
  __shared__ float sh[2048];
  const int b = blockIdx.x >> 1;
  const int role = blockIdx.x & 1;
  const int t = threadIdx.x;
  if (role == 0) {
    const int d = t & 127, g = t >> 7;
    const float* pA = partA + (size_t)(b * CH + g * 16) * GAT_D + d;
    const float* pP = partP + (size_t)(b * CH + g * 16) * GAT_D + d;
    float la[16], lp[16];
    float sA = 0.f, sP = 0.f;
#pragma unroll
    for (int i = 0; i < 16; ++i) {
      la[i] = pA[i * GAT_D];
      sA += la[i];
      lp[i] = pP[i * GAT_D];
      sP += lp[i];
    }
    totA[g][d] = sA;
    totP[g][d] = sP;
    __syncthreads();
    float offA = 0.f, offP = 0.f;
    for (int gg = 0; gg < g; ++gg) offA += totA[gg][d];
    for (int gg = g + 1; gg < 8; ++gg) offP += totP[gg][d];
    float run = offA;
#pragma unroll
    for (int i = 0; i < 16; ++i) {
      baseA[(size_t)(b * (CH + 1) + g * 16 + i) * GAT_D + d] = run;
      run += la[i];
    }
    if (g == 7) baseA[(size_t)(b * (CH + 1) + CH) * GAT_D + d] = run;
    run = offP;
#pragma unroll
    for (int i = 15; i >= 0; --i) {
      baseP[(size_t)(b * CH + g * 16 + i) * GAT_D + d] = run;
      run += lp[i];
    }
  } else {
    sh[t] = s2s[b * GAT_N + t];
    sh[t + 1024] = s2s[b * GAT_N + t + 1024];
    __syncthreads();
#pragma unroll
    for (int rr = 0; rr < 2; ++rr) {
      const int j = t + rr * 1024;
      const float s1v = s1s[b * GAT_N + j];
      const float tt = -s1v;
      int lo = 0, hi = GAT_N;
      while (lo < hi) {
        const int mid = (lo + hi) >> 1;
        if (sh[mid] < tt)
          lo = mid + 1;
        else
          hi = mid;
      }
      const float e1 = __expf(s1v), e2 = __expf(GAT_ALPHA * s1v);
      float den = 0.f;
      if (lo < GAT_N) den += e1 * sufDenP[b * GAT_N + lo];
      if (lo > 0) den += e2 * preDenA[b * GAT_N + lo - 1];
      const float inv = 1.f / den;
      pArr[b * GAT_N + j] = lo;
      c1[b * GAT_N + j] = e1 * inv;
      c2[b * GAT_N + j] = e2 * inv;
    }
  }
}

// ---------------------------------------------------------------------------
// K5: one wave per row (s1-sorted order for chunk locality). Combine chunk
// base + <=16-step within-chunk float2 cumsum for both branches, relu,
// scatter-write by original row id. p==0 / p==N are naturally empty loops
// with zero bases -- no special cases.
// ---------------------------------------------------------------------------
__global__ __launch_bounds__(256) void k5_out(const float* __restrict__ hs,
                                              const float* __restrict__ wA,
                                              const float* __restrict__ wP,
                                              const float* __restrict__ baseA,
                                              const float* __restrict__ baseP,
                                              const int* __restrict__ pArr,
                                              const float* __restrict__ c1,
                                              const float* __restrict__ c2,
                                              const int* __restrict__ rids,
                                              float* __restrict__ out) {
  const int wave = threadIdx.x >> 6, lane = threadIdx.x & 63;
  const int j = blockIdx.x * 4 + wave;  // sorted row index
  const int b = j >> 11;
  const int jr = b * GAT_N + (j & 2047);
  const int p = pArr[jr];
  const float cc1 = c1[jr], cc2 = c2[jr];
  const int rid = rids[jr];
  const float2* hs2 = (const float2*)(hs + (size_t)b * GAT_N * GAT_D);
  const float* wAb = wA + b * GAT_N;
  const float* wPb = wP + b * GAT_N;

  const int cA = p >> 4;
  float2 accA = ((const float2*)(baseA + (size_t)(b * (CH + 1) + cA) * GAT_D))[lane];
  for (int q = cA * CL; q < p; ++q) {
    const float w = wAb[q];
    const float2 hv = hs2[(size_t)q * 64 + lane];
    accA.x = fmaf(w, hv.x, accA.x);
    accA.y = fmaf(w, hv.y, accA.y);
  }

  const int pP = p < GAT_N ? p : GAT_N - 1;
  const int cP = pP >> 4;
  float2 accP = ((const float2*)(baseP + (size_t)(b * CH + cP) * GAT_D))[lane];
  const int qend = cP * CL + CL;
  for (int q = p; q < qend; ++q) {
    const float w = wPb[q];
    const float2 hv = hs2[(size_t)q * 64 + lane];
    accP.x = fmaf(w, hv.x, accP.x);
    accP.y = fmaf(w, hv.y, accP.y);
  }

  const float vx = cc2 * accA.x + cc1 * accP.x;
  const float vy = cc2 * accA.y + cc1 * accP.y;
  ((float2*)out)[(size_t)(b * GAT_N + rid) * 64 + lane] =
      make_float2(fmaxf(vx, 0.f), fmaxf(vy, 0.f));
}

extern "C" void kernel_launch(void* const* d_in, const int* in_sizes, int n_in,
                              void* d_out, int out_size, void* d_ws, size_t ws_size,
                              hipStream_t stream) {
  (void)in_sizes;
  (void)n_in;
  (void)out_size;
  (void)ws_size;
  const float* x = (const float*)d_in[0];
  const float* W = (const float*)d_in[1];
  const float* a = (const float*)d_in[2];
  float* out = (float*)d_out;
  float* wsf = (float*)d_ws;

  const size_t HN = (size_t)GAT_ROWS * GAT_D;
  size_t o = 0;
  float* s1v = wsf + o;      o += GAT_ROWS;
  float* s2v = wsf + o;      o += GAT_ROWS;
  float* s2s = wsf + o;      o += GAT_ROWS;
  int* idxs = (int*)(wsf + o); o += GAT_ROWS;
  float* s1s = wsf + o;      o += GAT_ROWS;
  int* rids = (int*)(wsf + o); o += GAT_ROWS;
  float* preDenA = wsf + o;  o += GAT_ROWS;
  float* sufDenP = wsf + o;  o += GAT_ROWS;
  float* wAr = wsf + o;      o += GAT_ROWS;
  float* wPr = wsf + o;      o += GAT_ROWS;
  int* pArr = (int*)(wsf + o); o += GAT_ROWS;
  float* c1 = wsf + o;       o += GAT_ROWS;
  float* c2 = wsf + o;       o += GAT_ROWS;
  float* partA = wsf + o;    o += (size_t)GAT_B * CH * GAT_D;
  float* partP = wsf + o;    o += (size_t)GAT_B * CH * GAT_D;
  float* baseA = wsf + o;    o += (size_t)GAT_B * (CH + 1) * GAT_D;
  float* baseP = wsf + o;    o += (size_t)GAT_B * CH * GAT_D;
  float* h = wsf + o;        o += HN;
  float* hs = wsf + o;       o += HN;

  k1_gemm<<<1024, 256, 0, stream>>>(x, W, a, h, s1v, s2v);
  k2_sort<<<2 * GAT_B, 1024, 0, stream>>>(s1v, s2v, s2s, idxs, s1s, rids, wAr, wPr,
                                          preDenA, sufDenP);
  k3_permute<<<GAT_B * CH, 128, 0, stream>>>(h, idxs, wAr, wPr, hs, partA, partP);
  k3b_prep<<<2 * GAT_B, 1024, 0, stream>>>(s1s, s2s, preDenA, sufDenP, partA, partP,
                                           baseA, baseP, pArr, c1, c2);
  k5_out<<<GAT_ROWS / 4, 256, 0, stream>>>(hs, wAr, wPr, baseA, baseP, pArr, c1, c2,
                                           rids, out);
}

// Round 7
// 82.051 us; speedup vs baseline: 1.6260x; 1.1113x over previous
//
#include <hip/hip_runtime.h>
#include <hip/hip_bf16.h>
#include <cstddef>

#define GAT_B 16
#define GAT_N 2048
#define GAT_D 128
#define GAT_ROWS (GAT_B * GAT_N)
#define CH 128          // position-chunks per batch
#define CL 16           // positions per chunk
#define GAT_ALPHA 0.2f

typedef __attribute__((ext_vector_type(8))) short short8v;  // 8 bf16 (4 VGPRs)
typedef __attribute__((ext_vector_type(4))) float f32x4;

__device__ __forceinline__ void cvt_hilo(float x, unsigned short& hi, unsigned short& lo) {
  union { float f; unsigned u; } a;
  a.f = x;
  hi = (unsigned short)(a.u >> 16);
  union { unsigned u; float f; } b;
  b.u = (unsigned)hi << 16;
  union { float f; unsigned u; } c;
  c.f = x - b.f;
  lo = (unsigned short)(c.u >> 16);
}

// ---------------------------------------------------------------------------
// K0: scatter W (fp32 [k][n]) into bf16 hi/lo B-fragment layout:
//   Wfrag[((ks*4+g)*128 + n)*8 + j] = bf16(W[ks*32+g*8+j][n])
// so lane l reading 16B at ((ks*4+(l>>4))*128 + col)*8 gets exactly its
// mfma_16x16x32 B-fragment. 2048 threads, one (ks,g,n) triple each.
// ---------------------------------------------------------------------------
__global__ __launch_bounds__(256) void k0_wfrag(const float* __restrict__ W,
                                                unsigned short* __restrict__ WfH,
                                                unsigned short* __restrict__ WfL) {
  const int t = blockIdx.x * 256 + threadIdx.x;  // 0..2047
  const int n = t & 127, g = (t >> 7) & 3, ks = t >> 9;
  short8v vh, vl;
#pragma unroll
  for (int j = 0; j < 8; ++j) {
    const int k = ks * 32 + g * 8 + j;
    unsigned short hi, lo;
    cvt_hilo(W[k * 128 + n], hi, lo);
    vh[j] = (short)hi;
    vl[j] = (short)lo;
  }
  *(short8v*)&WfH[t * 8] = vh;
  *(short8v*)&WfL[t * 8] = vl;
}

// ---------------------------------------------------------------------------
// K1: h = x @ W via MFMA bf16 3-term split (x_hi*W_hi + x_lo*W_hi + x_hi*W_lo).
// 512 blocks x 256 threads (4 waves). Block tile 64 rows x 128 cols; wave =
// 64 rows x 32 cols (mt=4, nt=2). LDS only 32KB (x hi/lo, XOR-swizzled);
// W-fragments read straight from global (L2-resident 32KB) into registers.
// s1/s2: per-wave 32-col partial dots written to GLOBAL (s1part/s2part[4][..]),
// summed in K2 -- no cross-wave LDS, single barrier, replay-race-free by
// construction (round-6 post-timing divergence was in the 132KB-LDS variant).
// ---------------------------------------------------------------------------
__global__ __launch_bounds__(256) void k1_gemm(const float* __restrict__ x,
                                               const unsigned short* __restrict__ WfHg,
                                               const unsigned short* __restrict__ WfLg,
                                               const float* __restrict__ aa,
                                               float* __restrict__ h,
                                               float* __restrict__ s1part,
                                               float* __restrict__ s2part) {
  __shared__ unsigned short xH[64 * 128];  // 16KB, [row][slot^row&7]
  __shared__ unsigned short xL[64 * 128];  // 16KB
  const int tid = threadIdx.x;
  const int row0 = blockIdx.x * 64;

  // x stage: fp32 -> bf16 hi/lo, [row][k] with slot^(row&7) swizzle
#pragma unroll
  for (int p = 0; p < 8; ++p) {
    const int row = p * 8 + (tid >> 5);
    const int f4 = tid & 31;
    const float4 v = ((const float4*)(x + (size_t)(row0 + row) * GAT_D))[f4];
    unsigned short h0, h1, h2, h3, l0, l1, l2, l3;
    cvt_hilo(v.x, h0, l0);
    cvt_hilo(v.y, h1, l1);
    cvt_hilo(v.z, h2, l2);
    cvt_hilo(v.w, h3, l3);
    const int slot = (f4 >> 1) ^ (row & 7);
    const int base = row * 128 + slot * 8 + (f4 & 1) * 4;
    *(ushort4*)&xH[base] = make_ushort4(h0, h1, h2, h3);
    *(ushort4*)&xL[base] = make_ushort4(l0, l1, l2, l3);
  }

  const int w = tid >> 6, l = tid & 63;
  const int wc0 = w * 32;
  const int g = l >> 4, c16 = l & 15;

  // B-fragments: registers, straight from global (no LDS round-trip)
  short8v bh[4][2], bl[4][2];
#pragma unroll
  for (int ks = 0; ks < 4; ++ks)
#pragma unroll
    for (int nt = 0; nt < 2; ++nt) {
      const int bi = ((ks * 4 + g) * 128 + wc0 + nt * 16 + c16) * 8;
      bh[ks][nt] = *(const short8v*)&WfHg[bi];
      bl[ks][nt] = *(const short8v*)&WfLg[bi];
    }

  __syncthreads();

  f32x4 acc[4][2];
#pragma unroll
  for (int mt = 0; mt < 4; ++mt)
#pragma unroll
    for (int nt = 0; nt < 2; ++nt) acc[mt][nt] = (f32x4)(0.f);

#pragma unroll
  for (int ks = 0; ks < 4; ++ks) {
    short8v ah[4], al[4];
#pragma unroll
    for (int mt = 0; mt < 4; ++mt) {
      const int row = mt * 16 + c16;
      const int ai = row * 128 + (((ks * 4 + g) ^ (row & 7)) * 8);
      ah[mt] = *(const short8v*)&xH[ai];
      al[mt] = *(const short8v*)&xL[ai];
    }
#pragma unroll
    for (int mt = 0; mt < 4; ++mt) {
#pragma unroll
      for (int nt = 0; nt < 2; ++nt) {
        acc[mt][nt] = __builtin_amdgcn_mfma_f32_16x16x32_bf16(ah[mt], bh[ks][nt], acc[mt][nt], 0, 0, 0);
        acc[mt][nt] = __builtin_amdgcn_mfma_f32_16x16x32_bf16(al[mt], bh[ks][nt], acc[mt][nt], 0, 0, 0);
        acc[mt][nt] = __builtin_amdgcn_mfma_f32_16x16x32_bf16(ah[mt], bl[ks][nt], acc[mt][nt], 0, 0, 0);
      }
    }
  }

  // h store (C/D layout m89: row=(l>>4)*4+reg, col=l&15)
#pragma unroll
  for (int mt = 0; mt < 4; ++mt)
#pragma unroll
    for (int nt = 0; nt < 2; ++nt)
#pragma unroll
      for (int j = 0; j < 4; ++j)
        h[(size_t)(row0 + mt * 16 + g * 4 + j) * GAT_D + wc0 + nt * 16 + c16] =
            acc[mt][nt][j];

  // per-wave partial dots for s1/s2 (32 cols each), 16-lane shfl reduce,
  // c16==0 lanes write global; K2 sums the 4 wave-partials.
  float a1v[2], a2v[2];
#pragma unroll
  for (int nt = 0; nt < 2; ++nt) {
    a1v[nt] = aa[wc0 + nt * 16 + c16];
    a2v[nt] = aa[128 + wc0 + nt * 16 + c16];
  }
#pragma unroll
  for (int mt = 0; mt < 4; ++mt) {
#pragma unroll
    for (int j = 0; j < 4; ++j) {
      float t1 = acc[mt][0][j] * a1v[0] + acc[mt][1][j] * a1v[1];
      float t2 = acc[mt][0][j] * a2v[0] + acc[mt][1][j] * a2v[1];
#pragma unroll
      for (int off = 1; off < 16; off <<= 1) {
        t1 += __shfl_xor(t1, off);
        t2 += __shfl_xor(t2, off);
      }
      if (c16 == 0) {
        const int row = row0 + mt * 16 + g * 4 + j;
        s1part[w * GAT_ROWS + row] = t1;
        s2part[w * GAT_ROWS + row] = t2;
      }
    }
  }
}

// ---------------------------------------------------------------------------
// K2: 32 blocks (2 per batch), 1024 threads. Sums the 4 wave-partials of
// s1/s2 on load.
//  even block: bitonic-sort s2 (w/ indices) -> s2s/idxs, exp weights wA/wP,
//              + both den scans (hierarchical shfl scan, 2 barriers).
//  odd block:  bitonic-sort key=-s1 -> s1s (desc) / rids.
// ---------------------------------------------------------------------------
__global__ __launch_bounds__(1024) void k2_sort(const float* __restrict__ s1part,
                                                const float* __restrict__ s2part,
                                                float* __restrict__ s2s,
                                                int* __restrict__ idxs,
                                                float* __restrict__ s1s,
                                                int* __restrict__ rids,
                                                float* __restrict__ wA,
                                                float* __restrict__ wP,
                                                float* __restrict__ preDenA,
                                                float* __restrict__ sufDenP) {
  __shared__ float v[2048];
  __shared__ int id[2048];
  __shared__ float wtotA[16];
  __shared__ float wtotP[16];
  const int tid = threadIdx.x;
  const int b = blockIdx.x >> 1;
  const int half = blockIdx.x & 1;
  const int i0 = tid, i1 = tid + 1024;
  const float* src = (half == 0) ? s2part : s1part;
  {
    const int r0 = b * GAT_N + i0, r1 = b * GAT_N + i1;
    float v0 = src[r0] + src[GAT_ROWS + r0] + src[2 * GAT_ROWS + r0] + src[3 * GAT_ROWS + r0];
    float v1 = src[r1] + src[GAT_ROWS + r1] + src[2 * GAT_ROWS + r1] + src[3 * GAT_ROWS + r1];
    if (half == 1) {
      v0 = -v0;
      v1 = -v1;
    }
    v[i0] = v0;
    v[i1] = v1;
  }
  id[i0] = i0;
  id[i1] = i1;
  for (int k = 2; k <= 2048; k <<= 1) {
    for (int j = k >> 1; j > 0; j >>= 1) {
      __syncthreads();
      const int i = ((tid & ~(j - 1)) << 1) | (tid & (j - 1));
      const int ixj = i | j;
      const bool up = (i & k) == 0;
      const float va = v[i], vb = v[ixj];
      if (up ? (va > vb) : (va < vb)) {
        v[i] = vb;
        v[ixj] = va;
        const int ta = id[i];
        id[i] = id[ixj];
        id[ixj] = ta;
      }
    }
  }
  __syncthreads();
  if (half == 1) {
    s1s[b * GAT_N + i0] = -v[i0];
    s1s[b * GAT_N + i1] = -v[i1];
    rids[b * GAT_N + i0] = id[i0];
    rids[b * GAT_N + i1] = id[i1];
    return;
  }
  s2s[b * GAT_N + i0] = v[i0];
  s2s[b * GAT_N + i1] = v[i1];
  idxs[b * GAT_N + i0] = id[i0];
  idxs[b * GAT_N + i1] = id[i1];

  const int lane = tid & 63, w = tid >> 6;
  const float aL = __expf(GAT_ALPHA * v[2 * tid]);
  const float aR = __expf(GAT_ALPHA * v[2 * tid + 1]);
  const float pL = __expf(v[2047 - 2 * tid]);
  const float pR = __expf(v[2046 - 2 * tid]);
  wA[b * GAT_N + 2 * tid] = aL;
  wA[b * GAT_N + 2 * tid + 1] = aR;
  wP[b * GAT_N + 2047 - 2 * tid] = pL;
  wP[b * GAT_N + 2046 - 2 * tid] = pR;
  float sA = aL + aR, sP = pL + pR;
#pragma unroll
  for (int off = 1; off < 64; off <<= 1) {
    const float tA = __shfl_up(sA, off);
    const float tP = __shfl_up(sP, off);
    if (lane >= off) {
      sA += tA;
      sP += tP;
    }
  }
  if (lane == 63) {
    wtotA[w] = sA;
    wtotP[w] = sP;
  }
  __syncthreads();
  float offA = 0.f, offP = 0.f;
  for (int ww = 0; ww < w; ++ww) {
    offA += wtotA[ww];
    offP += wtotP[ww];
  }
  const float inclA = offA + sA;
  const float inclP = offP + sP;
  preDenA[b * GAT_N + 2 * tid] = inclA - aR;
  preDenA[b * GAT_N + 2 * tid + 1] = inclA;
  sufDenP[b * GAT_N + 2047 - 2 * tid] = inclP - pR;
  sufDenP[b * GAT_N + 2046 - 2 * tid] = inclP;
}

// ---------------------------------------------------------------------------
// K3: permute h into sorted order (hs[q] = h[idx[q]]) and per-chunk partial
// sums of w*hs. One block per (batch, chunk of 16 positions), 128 threads.
// ---------------------------------------------------------------------------
__global__ __launch_bounds__(128) void k3_permute(const float* __restrict__ h,
                                                  const int* __restrict__ idxs,
                                                  const float* __restrict__ wA,
                                                  const float* __restrict__ wP,
                                                  float* __restrict__ hs,
                                                  float* __restrict__ partA,
                                                  float* __restrict__ partP) {
  const int b = blockIdx.x >> 7, c = blockIdx.x & (CH - 1);
  const int d = threadIdx.x;
  const int q0 = c * CL;
  const int* idxb = idxs + b * GAT_N;
  const float* hb = h + (size_t)b * GAT_N * GAT_D;
  float accA = 0.f, accP = 0.f;
#pragma unroll
  for (int qq = 0; qq < CL; ++qq) {
    const int q = q0 + qq;
    const int j = idxb[q];
    const float hv = hb[(size_t)j * GAT_D + d];
    hs[((size_t)b * GAT_N + q) * GAT_D + d] = hv;
    accA = fmaf(wA[b * GAT_N + q], hv, accA);
    accP = fmaf(wP[b * GAT_N + q], hv, accP);
  }
  partA[(b * CH + c) * GAT_D + d] = accA;
  partP[(b * CH + c) * GAT_D + d] = accP;
}

// ---------------------------------------------------------------------------
// K3b: 32 blocks (2 per batch), 1024 threads.
//  role 0: scan chunk partials into exclusive prefix/suffix bases.
//  role 1: per-row prep: binary search p (s2s in LDS), den, c1, c2.
// ---------------------------------------------------------------------------
__global__ __launch_bounds__(1024) void k3b_prep(const float* __restrict__ s1s,
                                                 const float* __restrict__ s2s,
                                                 const float* __restrict__ preDenA,
                                                 const float* __restrict__ sufDenP,
                                                 const float* __restrict__ partA,
                                                 const float* __restrict__ partP,
                                                 float* __restrict__ baseA,
                                                 float* __restrict__ baseP,
                                                 int* __restrict__ pArr,
                                                 float* __restrict__ c1,
                                                 float* __restrict__ c2) {
  __shared__ float totA[8][128];
  __shared__ float totP[8][128];
  __shared__ float sh[2048];
  const int b = blockIdx.x >> 1;
  const int role = blockIdx.x & 1;
  const int t = threadIdx.x;
  if (role == 0) {
    const int d = t & 127, g = t >> 7;
    const float* pA = partA + (size_t)(b * CH + g * 16) * GAT_D + d;
    const float* pP = partP + (size_t)(b * CH + g * 16) * GAT_D + d;
    float la[16], lp[16];
    float sA = 0.f, sP = 0.f;
#pragma unroll
    for (int i = 0; i < 16; ++i) {
      la[i] = pA[i * GAT_D];
      sA += la[i];
      lp[i] = pP[i * GAT_D];
      sP += lp[i];
    }
    totA[g][d] = sA;
    totP[g][d] = sP;
    __syncthreads();
    float offA = 0.f, offP = 0.f;
    for (int gg = 0; gg < g; ++gg) offA += totA[gg][d];
    for (int gg = g + 1; gg < 8; ++gg) offP += totP[gg][d];
    float run = offA;
#pragma unroll
    for (int i = 0; i < 16; ++i) {
      baseA[(size_t)(b * (CH + 1) + g * 16 + i) * GAT_D + d] = run;
      run += la[i];
    }
    if (g == 7) baseA[(size_t)(b * (CH + 1) + CH) * GAT_D + d] = run;
    run = offP;
#pragma unroll
    for (int i = 15; i >= 0; --i) {
      baseP[(size_t)(b * CH + g * 16 + i) * GAT_D + d] = run;
      run += lp[i];
    }
  } else {
    sh[t] = s2s[b * GAT_N + t];
    sh[t + 1024] = s2s[b * GAT_N + t + 1024];
    __syncthreads();
#pragma unroll
    for (int rr = 0; rr < 2; ++rr) {
      const int j = t + rr * 1024;
      const float s1v = s1s[b * GAT_N + j];
      const float tt = -s1v;
      int lo = 0, hi = GAT_N;
      while (lo < hi) {
        const int mid = (lo + hi) >> 1;
        if (sh[mid] < tt)
          lo = mid + 1;
        else
          hi = mid;
      }
      const float e1 = __expf(s1v), e2 = __expf(GAT_ALPHA * s1v);
      float den = 0.f;
      if (lo < GAT_N) den += e1 * sufDenP[b * GAT_N + lo];
      if (lo > 0) den += e2 * preDenA[b * GAT_N + lo - 1];
      const float inv = 1.f / den;
      pArr[b * GAT_N + j] = lo;
      c1[b * GAT_N + j] = e1 * inv;
      c2[b * GAT_N + j] = e2 * inv;
    }
  }
}

// ---------------------------------------------------------------------------
// K5: one wave per row (s1-sorted order for chunk locality). Combine chunk
// base + <=16-step within-chunk float2 cumsum, relu, scatter by row id.
// ---------------------------------------------------------------------------
__global__ __launch_bounds__(256) void k5_out(const float* __restrict__ hs,
                                              const float* __restrict__ wA,
                                              const float* __restrict__ wP,
                                              const float* __restrict__ baseA,
                                              const float* __restrict__ baseP,
                                              const int* __restrict__ pArr,
                                              const float* __restrict__ c1,
                                              const float* __restrict__ c2,
                                              const int* __restrict__ rids,
                                              float* __restrict__ out) {
  const int wave = threadIdx.x >> 6, lane = threadIdx.x & 63;
  const int j = blockIdx.x * 4 + wave;  // sorted row index
  const int b = j >> 11;
  const int jr = b * GAT_N + (j & 2047);
  const int p = pArr[jr];
  const float cc1 = c1[jr], cc2 = c2[jr];
  const int rid = rids[jr];
  const float2* hs2 = (const float2*)(hs + (size_t)b * GAT_N * GAT_D);
  const float* wAb = wA + b * GAT_N;
  const float* wPb = wP + b * GAT_N;

  const int cA = p >> 4;
  float2 accA = ((const float2*)(baseA + (size_t)(b * (CH + 1) + cA) * GAT_D))[lane];
  for (int q = cA * CL; q < p; ++q) {
    const float w = wAb[q];
    const float2 hv = hs2[(size_t)q * 64 + lane];
    accA.x = fmaf(w, hv.x, accA.x);
    accA.y = fmaf(w, hv.y, accA.y);
  }

  const int pP = p < GAT_N ? p : GAT_N - 1;
  const int cP = pP >> 4;
  float2 accP = ((const float2*)(baseP + (size_t)(b * CH + cP) * GAT_D))[lane];
  const int qend = cP * CL + CL;
  for (int q = p; q < qend; ++q) {
    const float w = wPb[q];
    const float2 hv = hs2[(size_t)q * 64 + lane];
    accP.x = fmaf(w, hv.x, accP.x);
    accP.y = fmaf(w, hv.y, accP.y);
  }

  const float vx = cc2 * accA.x + cc1 * accP.x;
  const float vy = cc2 * accA.y + cc1 * accP.y;
  ((float2*)out)[(size_t)(b * GAT_N + rid) * 64 + lane] =
      make_float2(fmaxf(vx, 0.f), fmaxf(vy, 0.f));
}

extern "C" void kernel_launch(void* const* d_in, const int* in_sizes, int n_in,
                              void* d_out, int out_size, void* d_ws, size_t ws_size,
                              hipStream_t stream) {
  (void)in_sizes;
  (void)n_in;
  (void)out_size;
  (void)ws_size;
  const float* x = (const float*)d_in[0];
  const float* W = (const float*)d_in[1];
  const float* a = (const float*)d_in[2];
  float* out = (float*)d_out;
  float* wsf = (float*)d_ws;

  const size_t HN = (size_t)GAT_ROWS * GAT_D;
  size_t o = 0;
  float* s1part = wsf + o;   o += 4 * GAT_ROWS;
  float* s2part = wsf + o;   o += 4 * GAT_ROWS;
  float* s2s = wsf + o;      o += GAT_ROWS;
  int* idxs = (int*)(wsf + o); o += GAT_ROWS;
  float* s1s = wsf + o;      o += GAT_ROWS;
  int* rids = (int*)(wsf + o); o += GAT_ROWS;
  float* preDenA = wsf + o;  o += GAT_ROWS;
  float* sufDenP = wsf + o;  o += GAT_ROWS;
  float* wAr = wsf + o;      o += GAT_ROWS;
  float* wPr = wsf + o;      o += GAT_ROWS;
  int* pArr = (int*)(wsf + o); o += GAT_ROWS;
  float* c1 = wsf + o;       o += GAT_ROWS;
  float* c2 = wsf + o;       o += GAT_ROWS;
  float* partA = wsf + o;    o += (size_t)GAT_B * CH * GAT_D;
  float* partP = wsf + o;    o += (size_t)GAT_B * CH * GAT_D;
  float* baseA = wsf + o;    o += (size_t)GAT_B * (CH + 1) * GAT_D;
  float* baseP = wsf + o;    o += (size_t)GAT_B * CH * GAT_D;
  unsigned short* WfH = (unsigned short*)(wsf + o); o += 8192;  // 16384 ushort
  unsigned short* WfL = (unsigned short*)(wsf + o); o += 8192;
  float* h = wsf + o;        o += HN;
  float* hs = wsf + o;       o += HN;

  k0_wfrag<<<8, 256, 0, stream>>>(W, WfH, WfL);
  k1_gemm<<<512, 256, 0, stream>>>(x, WfH, WfL, a, h, s1part, s2part);
  k2_sort<<<2 * GAT_B, 1024, 0, stream>>>(s1part, s2part, s2s, idxs, s1s, rids, wAr, wPr,
                                          preDenA, sufDenP);
  k3_permute<<<GAT_B * CH, 128, 0, stream>>>(h, idxs, wAr, wPr, hs, partA, partP);
  k3b_prep<<<2 * GAT_B, 1024, 0, stream>>>(s1s, s2s, preDenA, sufDenP, partA, partP,
                                           baseA, baseP, pArr, c1, c2);
  k5_out<<<GAT_ROWS / 4, 256, 0, stream>>>(hs, wAr, wPr, baseA, baseP, pArr, c1, c2,
                                           rids, out);
}